// Round 10
// baseline (883.106 us; speedup 1.0000x reference)
//
#include <hip/hip_runtime.h>
#include <math.h>

#define BATCH 256
#define SEQ   2048
#define HID   128
#define VOCAB 50000
#define RPB   4
#define NRB   (BATCH / RPB)     // 64 blocks
#define NTHR  256
#define HPAD  160               // f16 row stride (320 B): banks spread, <=2-way

typedef _Float16 v2h __attribute__((ext_vector_type(2)));
typedef _Float16 v8h __attribute__((ext_vector_type(8)));
typedef float    v4f __attribute__((ext_vector_type(4)));

template<int CTRL>
__device__ __forceinline__ float dpp_movf(float x) {
    return __builtin_bit_cast(float,
        __builtin_amdgcn_update_dpp(0, __builtin_bit_cast(int, x),
                                    CTRL, 0xF, 0xF, false));
}
__device__ __forceinline__ float quad_reduce(float x) {
    x += dpp_movf<0xB1>(x);
    x += dpp_movf<0x4E>(x);
    return x;
}
__device__ __forceinline__ float fast_rcp(float x) { return __builtin_amdgcn_rcpf(x); }
__device__ __forceinline__ float dot2(v2h a, v2h b, float c) {
    return __builtin_amdgcn_fdot2(a, b, c, false);
}
__device__ __forceinline__ float fast_tanhf(float z) {
    return 1.0f - 2.0f * fast_rcp(__builtin_amdgcn_exp2f(z * 2.885390081777927f) + 1.0f);
}
#define BCH(u) __builtin_bit_cast(v2h, (u))

// lgkmcnt-only barrier: LDS producer->consumer visibility without draining
// the in-flight Y-gather global loads (vmcnt) each phase.
__device__ __forceinline__ void barrier_lds() {
    asm volatile("s_waitcnt lgkmcnt(0)\n\ts_barrier" ::: "memory");
}

// D-reg select: value for real row rg out of v4f (static cndmask tree)
__device__ __forceinline__ float sel4(v4f c, bool b0, bool b1) {
    const float lo = b0 ? c.y : c.x;
    const float hi = b0 ? c.w : c.z;
    return b1 ? hi : lo;
}

// ---------------- Y = emb @ W_ih[0] + b[0]  (f16 out) ----------------
__global__ __launch_bounds__(512, 2) void emb_proj_kernel(
    const float* __restrict__ emb, const float* __restrict__ W_ih,
    const float* __restrict__ bias, _Float16* __restrict__ Y)
{
    const int tid  = threadIdx.x;
    const int wave = tid >> 6;
    const int lane = tid & 63;
    const int j    = wave * 16 + (lane >> 2);
    const int q    = lane & 3;

    __shared__ __align__(16) _Float16 xr[HID];

    v2h w[16];
#pragma unroll
    for (int i = 0; i < 16; ++i) {
        const int k = q * 32 + 2 * i;
        w[i] = v2h{(_Float16)W_ih[k * HID + j], (_Float16)W_ih[(k + 1) * HID + j]};
    }
    const float bj = bias[j];
    const float4* embf4 = (const float4*)emb;

    for (int r = blockIdx.x; r < VOCAB; r += gridDim.x) {
        if (tid < 32) {
            float4 v = embf4[(size_t)r * 32 + tid];
            uint a01 = __builtin_bit_cast(uint, __builtin_amdgcn_cvt_pkrtz(v.x, v.y));
            uint a23 = __builtin_bit_cast(uint, __builtin_amdgcn_cvt_pkrtz(v.z, v.w));
            ((uint2*)&xr[0])[tid] = uint2{a01, a23};
        }
        __syncthreads();
        const uint4* xp = (const uint4*)&xr[0] + q * 4;
        float acc = 0.f;
#pragma unroll
        for (int i = 0; i < 4; ++i) {
            const uint4 xu = xp[i];
            acc = dot2(BCH(xu.x), w[4*i+0], acc);
            acc = dot2(BCH(xu.y), w[4*i+1], acc);
            acc = dot2(BCH(xu.z), w[4*i+2], acc);
            acc = dot2(BCH(xu.w), w[4*i+3], acc);
        }
        acc = quad_reduce(acc) + bj;
        if (q == 0) Y[(size_t)r * HID + j] = (_Float16)acc;
        __syncthreads();
    }
}

// ------------- batched recurrent: 4 rows/block, dup-row MFMA, full-wave epi -------------
// 4 waves; wave w owns cols [32w, 32w+32) (tiles T0=2w, T1=2w+1) of both layers.
// A rows: row m holds real row m&3 (4x duplicated) -> D reg r = real row r for
// every lane; lane-group rg = lane>>4 owns real row rg (select reg rg).
// Phase t: h0(t) = tanh(Whh0 h0(t-1) + Y[tok_r(t)]);
//          h1(t-1) = tanh(Wih1 h0(t-1) + Whh1 h1(t-2) + b1). One barrier/phase.
__global__ __launch_bounds__(NTHR, 1) void rnn_b4_kernel(
    const int*      __restrict__ x,        // [B, T]
    const int*      __restrict__ lengths,  // [B]
    const _Float16* __restrict__ Y,        // [VOCAB, 128]
    const float*    __restrict__ W_ih,     // [2, 128, 128] (layer 1 used)
    const float*    __restrict__ W_hh,     // [2, 128, 128]
    const float*    __restrict__ bias,     // [2, 128] (layer 1 used)
    const float*    __restrict__ cls_w,    // [128]
    const float*    __restrict__ cls_b,    // [1]
    float*          __restrict__ out)      // [B]
{
    const int blk  = blockIdx.x;
    const int tid  = threadIdx.x;
    const int w    = tid >> 6;
    const int lane = tid & 63;
    const int rg   = lane >> 4;          // A: k-group | D/epilogue: real row
    const int ln   = lane & 15;          // A: row m (data = row m&3) | D: col n
    const int c0   = w * 32 + ln;        // tile 0 col
    const int c1   = c0 + 16;            // tile 1 col
    const int rb   = blk * RPB;
    const bool rgb0 = (rg & 1) != 0;
    const bool rgb1 = (rg & 2) != 0;

    __shared__ ushort xtok[RPB][SEQ];                       // 16 KB
    __shared__ __align__(16) _Float16 h0s[2][RPB][HPAD];
    __shared__ __align__(16) _Float16 h1s[2][RPB][HPAD];
    __shared__ float clsb[RPB][HID];

    // stage tokens as u16 (VOCAB < 65536), coalesced
    for (int i = tid; i < RPB * SEQ; i += NTHR) {
        const int r = i >> 11, t = i & (SEQ - 1);
        xtok[r][t] = (ushort)x[(rb + r) * SEQ + t];
    }
    for (int i = tid; i < 2 * RPB * HPAD; i += NTHR) {
        ((_Float16*)h0s)[i] = (_Float16)0.f;
        ((_Float16*)h1s)[i] = (_Float16)0.f;
    }

    const int lenr = lengths[rb + rg];
    const int Tmax = max(max(lengths[rb], lengths[rb + 1]),
                         max(lengths[rb + 2], lengths[rb + 3]));

    // B-fragments [tile][kt]: lane 16*kg+n holds B[k=32kt+8kg+e][n] (R8-verified)
    v8h Bhh0[2][4], Bih1[2][4], Bhh1[2][4];
#pragma unroll
    for (int kt = 0; kt < 4; ++kt) {
#pragma unroll
        for (int e = 0; e < 8; ++e) {
            const int k = kt * 32 + rg * 8 + e;
            Bhh0[0][kt][e] = (_Float16)W_hh[k * HID + c0];
            Bhh0[1][kt][e] = (_Float16)W_hh[k * HID + c1];
            Bih1[0][kt][e] = (_Float16)W_ih[HID * HID + k * HID + c0];
            Bih1[1][kt][e] = (_Float16)W_ih[HID * HID + k * HID + c1];
            Bhh1[0][kt][e] = (_Float16)W_hh[HID * HID + k * HID + c0];
            Bhh1[1][kt][e] = (_Float16)W_hh[HID * HID + k * HID + c1];
        }
    }
    const float b1c0 = bias[HID + c0];
    const float b1c1 = bias[HID + c1];

    __syncthreads();                           // tokens + zeroed h visible

    const ushort* Yu = (const ushort*)Y;
    // Y ring (depth 2): this lane's (row rg, cols c0,c1)
    ushort yA0, yA1, yB0, yB1;
    { const int tk = xtok[rg][0]; yA0 = Yu[(size_t)tk * HID + c0]; yA1 = Yu[(size_t)tk * HID + c1]; }
    { const int tk = xtok[rg][1]; yB0 = Yu[(size_t)tk * HID + c0]; yB1 = Yu[(size_t)tk * HID + c1]; }

    // persistent state for (row rg, cols c0/c1): layer0 p0*, layer1 p1*
    float p00 = 0.f, p01 = 0.f, p10 = 0.f, p11 = 0.f;

#define PHASE(RD, WR, Y0, Y1, TT)                                            \
    {                                                                        \
        const char* a0b = (const char*)&h0s[RD][0][0] + (ln & 3) * (HPAD*2); \
        const char* a1b = (const char*)&h1s[RD][0][0] + (ln & 3) * (HPAD*2); \
        v8h A0[4], A1[4];                                                    \
        _Pragma("unroll")                                                    \
        for (int kt = 0; kt < 4; ++kt) {                                     \
            A0[kt] = *(const v8h*)(a0b + kt * 64 + rg * 16);                 \
            A1[kt] = *(const v8h*)(a1b + kt * 64 + rg * 16);                 \
        }                                                                    \
        const float yf0 = (float)__builtin_bit_cast(_Float16, Y0);           \
        const float yf1 = (float)__builtin_bit_cast(_Float16, Y1);           \
        {                                                                    \
            const int tn = (TT + 2 < SEQ) ? (TT + 2) : (SEQ - 1);            \
            const int tk = xtok[rg][tn];                                     \
            Y0 = Yu[(size_t)tk * HID + c0];                                  \
            Y1 = Yu[(size_t)tk * HID + c1];                                  \
        }                                                                    \
        v4f c00 = {0,0,0,0}, c01 = {0,0,0,0};                                \
        v4f c10 = {0,0,0,0}, c11 = {0,0,0,0};                                \
        _Pragma("unroll")                                                    \
        for (int kt = 0; kt < 4; ++kt) {                                     \
            c00 = __builtin_amdgcn_mfma_f32_16x16x32_f16(A0[kt], Bhh0[0][kt], c00, 0, 0, 0); \
            c01 = __builtin_amdgcn_mfma_f32_16x16x32_f16(A0[kt], Bhh0[1][kt], c01, 0, 0, 0); \
            c10 = __builtin_amdgcn_mfma_f32_16x16x32_f16(A0[kt], Bih1[0][kt], c10, 0, 0, 0); \
            c11 = __builtin_amdgcn_mfma_f32_16x16x32_f16(A0[kt], Bih1[1][kt], c11, 0, 0, 0); \
        }                                                                    \
        _Pragma("unroll")                                                    \
        for (int kt = 0; kt < 4; ++kt) {                                     \
            c10 = __builtin_amdgcn_mfma_f32_16x16x32_f16(A1[kt], Bhh1[0][kt], c10, 0, 0, 0); \
            c11 = __builtin_amdgcn_mfma_f32_16x16x32_f16(A1[kt], Bhh1[1][kt], c11, 0, 0, 0); \
        }                                                                    \
        const float s00 = sel4(c00, rgb0, rgb1);                             \
        const float s01 = sel4(c01, rgb0, rgb1);                             \
        const float s10 = sel4(c10, rgb0, rgb1);                             \
        const float s11 = sel4(c11, rgb0, rgb1);                             \
        const bool a0 = (TT < lenr);                                         \
        const bool a1 = (TT >= 1) && (TT <= lenr);                           \
        p00 = a0 ? fast_tanhf(s00 + yf0)  : p00;                             \
        p01 = a0 ? fast_tanhf(s01 + yf1)  : p01;                             \
        p10 = a1 ? fast_tanhf(s10 + b1c0) : p10;                             \
        p11 = a1 ? fast_tanhf(s11 + b1c1) : p11;                             \
        h0s[WR][rg][c0] = (_Float16)p00;                                     \
        h0s[WR][rg][c1] = (_Float16)p01;                                     \
        h1s[WR][rg][c0] = (_Float16)p10;                                     \
        h1s[WR][rg][c1] = (_Float16)p11;                                     \
        barrier_lds();                                                       \
    }

    int t = 0;
    for (;;) {
        PHASE(0, 1, yA0, yA1, t)
        ++t;
        if (t > Tmax) break;
        PHASE(1, 0, yB0, yB1, t)
        ++t;
        if (t > Tmax) break;
    }
#undef PHASE

    // classifier: out[rb+r] = sigmoid(h1_final[r] . cls_w + cls_b)
    clsb[rg][c0] = p10;
    clsb[rg][c1] = p11;
    __syncthreads();
    {
        // wave w reduces row w (RPB == 4 == #waves)
        float v = clsb[w][lane] * cls_w[lane] + clsb[w][64 + lane] * cls_w[64 + lane];
#pragma unroll
        for (int o = 32; o >= 1; o >>= 1) v += __shfl_xor(v, o, 64);
        if (lane == 0) {
            const float z = v + cls_b[0];
            out[rb + w] = fast_rcp(1.0f + __builtin_amdgcn_exp2f(-z * 1.4426950408889634f));
        }
    }
}

extern "C" void kernel_launch(void* const* d_in, const int* in_sizes, int n_in,
                              void* d_out, int out_size, void* d_ws, size_t ws_size,
                              hipStream_t stream) {
    const int*   x       = (const int*)  d_in[0];
    const int*   lengths = (const int*)  d_in[1];
    const float* emb     = (const float*)d_in[2];
    const float* W_ih    = (const float*)d_in[3];
    const float* W_hh    = (const float*)d_in[4];
    const float* bias    = (const float*)d_in[5];
    const float* cls_w   = (const float*)d_in[6];
    const float* cls_b   = (const float*)d_in[7];
    float*       out     = (float*)      d_out;

    _Float16* Yws = (_Float16*)d_ws;     // 50000*128*2 B = 12.8 MB

    emb_proj_kernel<<<2048, 512, 0, stream>>>(emb, W_ih, bias, Yws);
    rnn_b4_kernel<<<NRB, NTHR, 0, stream>>>(
        x, lengths, Yws, W_ih, W_hh, bias, cls_w, cls_b, out);
}